// Round 5
// baseline (438.031 us; speedup 1.0000x reference)
//
#include <hip/hip_runtime.h>
#include <stdint.h>

// Problem constants: x[8192,4096] f32, w[4096,4096] f32, bias[4096] f32.
#define NROW 8192
#define KDIM 4096
#define NOUT 4096

typedef __attribute__((ext_vector_type(4))) int i32x4;

// ---------------------------------------------------------------------------
// Kernel 1: sign-binarize f32 -> i8 {-1,+1} (bytes 0x01 / 0xFF), 4 per u32.
// One fused launch for x and w. float4 load -> u32 store, BW-bound.
// ---------------------------------------------------------------------------
__global__ __launch_bounds__(256)
void bin_i8_fused(const float* __restrict__ x, const float* __restrict__ w,
                  uint32_t* __restrict__ xq, uint32_t* __restrict__ wq,
                  int n4x, int n4tot) {
    int i = blockIdx.x * blockDim.x + threadIdx.x;
    const int stride = gridDim.x * blockDim.x;
    for (; i < n4tot; i += stride) {
        const float4* src;
        uint32_t* dst;
        int j;
        if (i < n4x) { src = (const float4*)x; dst = xq; j = i; }
        else         { src = (const float4*)w; dst = wq; j = i - n4x; }
        float4 v = src[j];
        uint32_t b0 = (v.x < 0.0f) ? 0xFFu : 0x01u;
        uint32_t b1 = (v.y < 0.0f) ? 0xFFu : 0x01u;
        uint32_t b2 = (v.z < 0.0f) ? 0xFFu : 0x01u;
        uint32_t b3 = (v.w < 0.0f) ? 0xFFu : 0x01u;
        dst[j] = b0 | (b1 << 8) | (b2 << 16) | (b3 << 24);
    }
}

// ---------------------------------------------------------------------------
// Kernel 2: i8 MFMA GEMM, 8-phase counted-vmcnt schedule + one-phase-ahead
// register pipelining of the LDS fragment reads.
//   C[n,o] = sum_k xq[n,k]*wq[o,k] + bias[o]   (exact i32 accumulate)
//
// Geometry: 256x256 tile, 512 threads = 8 waves (2Mx4N), per-wave 128x64 out
// = 8x4 frags of mfma_i32_16x16x64_i8. K-tile = 128 B, 4 staged half-tiles
// of 16KB. LDS [2dbuf][2khalf][256][64] = 128 KiB.
//
// r4 post-mortem: reads-then-MFMA inside each phase serialized the LDS pipe
// (768/384 cy per CU) against the matrix pipe (652 cy per SIMD) -> 33%
// MfmaUtil. Now each phase ISSUES THE NEXT PHASE'S ds_reads right after its
// data barrier, then MFMAs on registers loaded LAST phase. The compiler's
// counted lgkmcnt lets next-phase reads drain under the current MFMA burst.
//
// Read schedule (tile t: d=t&1, sd=d^1):
//   prologue      : read aL<-A[d0=0][0].lo, b0<-B[0][0]        (ph1 of t=0)
//   ph1: STAGE_A(sd,0); bar; read aH<-A[d][0].hi;     MFMA(acc0..3, aL,b0); bar
//   ph2: STAGE_B(sd,0); vmcnt(4); bar; FENCE;
//        read aL2<-A[d][1].lo, b1<-B[d][1];           MFMA(acc4..7, aH,b0); bar
//   ph3: STAGE_A(sd,1); bar; read aH2<-A[d][1].hi;    MFMA(acc0..3, aL2,b1); bar
//   ph4: STAGE_B(sd,1); vmcnt(4); bar; FENCE;
//        read aL<-A[sd][0].lo, b0<-B[sd][0];          MFMA(acc4..7, aH2,b1); bar
// Validity: ph2 reads [d][1] (staged as prev tile's A1,B1 -> retired by this
// vmcnt(4)+barrier); ph4 reads [sd][0] (this tile's A0,B0 -> retired by this
// vmcnt(4)+barrier). FENCE = compiler memory barrier so the reads cannot be
// hoisted above the s_barrier that establishes validity. WAR check: reads of
// [sd][0] in flight at ph4-exit are only overwritten by STAGE_A(sd,0) of
// tile t+2, four barriers later (t+1's ph1 writes [d][0]) -> safe.
// vmcnt accounting unchanged from r4 (never drains to 0 in the loop).
//
// Bank swizzle (r2/r4-verified, measured 0 conflicts): LDS slot s_l of row r
// holds global k-chunk s_l ^ ((r>>1)&3); linear gload_lds dest +
// pre-swizzled GLOBAL source; read slot = g ^ ((lr>>1)&3).
// ---------------------------------------------------------------------------
#define BM 256
#define BN 256
#define BKB 128
#define NT (KDIM / BKB)   // 32

__device__ __forceinline__ void gload_lds16(const void* g, void* l) {
    __builtin_amdgcn_global_load_lds(
        (const __attribute__((address_space(1))) uint32_t*)g,
        (__attribute__((address_space(3))) uint32_t*)l, 16, 0, 0);
}

__global__ __launch_bounds__(512, 2)
void i8_mfma_gemm(const uint8_t* __restrict__ xq, const uint8_t* __restrict__ wq,
                  const float* __restrict__ bias, float* __restrict__ out) {
    __shared__ __align__(16) uint8_t As[2][2][256][64];   // 64 KiB
    __shared__ __align__(16) uint8_t Bs[2][2][256][64];   // 64 KiB

    const int tid  = threadIdx.x;
    const int wid  = tid >> 6;        // 0..7
    const int lane = tid & 63;
    const int wr   = wid >> 2;        // 0..1 : 128-row slab
    const int wc   = wid & 3;         // 0..3 : 64-col slab
    const int lr   = lane & 15;
    const int g    = lane >> 4;       // k-chunk 0..3 within 64B k-half
    const int row0 = blockIdx.y * BM;
    const int col0 = blockIdx.x * BN;

    // Staging: half-tile = 256 rows x 64B = 1024 chunks of 16B; 2 per thread.
    // LDS dest linear in chunk index; global k-slot pre-swizzled (inverse):
    //   row = c>>2, s_l = c&3, s_g = (c&3) ^ ((c>>3)&3)
    const int c0 = wid * 64 + lane;   // 0..511
    const int c1 = 512 + c0;          // 512..1023
    const int s0 = (((c0 & 3) ^ ((c0 >> 3) & 3))) * 16;
    const int s1 = (((c1 & 3) ^ ((c1 >> 3) & 3))) * 16;
    const int r0 = c0 >> 2;
    const int r1 = c1 >> 2;

    const uint8_t* gA0 = xq + (size_t)(row0 + r0) * KDIM + s0;
    const uint8_t* gA1 = xq + (size_t)(row0 + r1) * KDIM + s1;
    const uint8_t* gB0 = wq + (size_t)(col0 + r0) * KDIM + s0;
    const uint8_t* gB1 = wq + (size_t)(col0 + r1) * KDIM + s1;

    const int sread = (g ^ ((lr >> 1) & 3)) * 16;   // swizzled read slot
    const int ra = wr * 128 + lr;                   // A fragment base row
    const int cb = wc * 64 + lr;                    // B fragment base col

#define STAGE_A(sd, kh, ko) do {                                  \
        uint8_t* _l = &As[sd][kh][0][0];                          \
        gload_lds16(gA0 + (ko) + (kh) * 64, _l + c0 * 16);        \
        gload_lds16(gA1 + (ko) + (kh) * 64, _l + c1 * 16);        \
    } while (0)
#define STAGE_B(sd, kh, ko) do {                                  \
        uint8_t* _l = &Bs[sd][kh][0][0];                          \
        gload_lds16(gB0 + (ko) + (kh) * 64, _l + c0 * 16);        \
        gload_lds16(gB1 + (ko) + (kh) * 64, _l + c1 * 16);        \
    } while (0)

#define RD_ALO(dst, dd, kh) do {                                       \
        _Pragma("unroll")                                              \
        for (int _m = 0; _m < 4; ++_m)                                 \
            dst[_m] = *(const i32x4*)&As[dd][kh][ra + _m * 16][sread]; \
    } while (0)
#define RD_AHI(dst, dd, kh) do {                                       \
        _Pragma("unroll")                                              \
        for (int _m = 0; _m < 4; ++_m)                                 \
            dst[_m] = *(const i32x4*)&As[dd][kh][ra + 64 + _m * 16][sread]; \
    } while (0)
#define RD_B(dst, dd, kh) do {                                         \
        _Pragma("unroll")                                              \
        for (int _n = 0; _n < 4; ++_n)                                 \
            dst[_n] = *(const i32x4*)&Bs[dd][kh][cb + _n * 16][sread]; \
    } while (0)
#define MFMA_BLK(mb, af, bf) do {                                      \
        _Pragma("unroll")                                              \
        for (int _m = 0; _m < 4; ++_m)                                 \
            _Pragma("unroll")                                          \
            for (int _n = 0; _n < 4; ++_n)                             \
                acc[(mb) + _m][_n] = __builtin_amdgcn_mfma_i32_16x16x64_i8( \
                    af[_m], bf[_n], acc[(mb) + _m][_n], 0, 0, 0);      \
    } while (0)
#define FENCE() asm volatile("" ::: "memory")

    i32x4 acc[8][4];
#pragma unroll
    for (int m = 0; m < 8; ++m)
#pragma unroll
        for (int n = 0; n < 4; ++n) acc[m][n] = (i32x4){0, 0, 0, 0};

    i32x4 aL[4], aH[4], aL2[4], aH2[4], b0[4], b1[4];

    // Prologue: stage tile 0 (issue order A0,B0,A1,B1 = wait order).
    STAGE_A(0, 0, 0);
    STAGE_B(0, 0, 0);
    STAGE_A(0, 1, 0);
    STAGE_B(0, 1, 0);
    asm volatile("s_waitcnt vmcnt(4)" ::: "memory");   // A-kh0,B-kh0 landed
    __builtin_amdgcn_s_barrier();
    FENCE();
    RD_ALO(aL, 0, 0);     // ph1 fragments for tile 0
    RD_B(b0, 0, 0);

#pragma unroll 1
    for (int t = 0; t < NT; ++t) {
        const int d  = t & 1;
        const int sd = d ^ 1;
        // Last tile re-stages its own sources (keeps vmcnt counts uniform;
        // lands in the dbuf that is no longer read -> harmless).
        const int ko = (t + 1 < NT ? t + 1 : t) * BKB;

        // ---------------- phase 1 ----------------
        STAGE_A(sd, 0, ko);
        __builtin_amdgcn_s_barrier();
        RD_AHI(aH, d, 0);                       // for ph2
        __builtin_amdgcn_s_setprio(1);
        MFMA_BLK(0, aL, b0);
        __builtin_amdgcn_s_setprio(0);
        __builtin_amdgcn_s_barrier();

        // ---------------- phase 2 ----------------
        STAGE_B(sd, 0, ko);
        asm volatile("s_waitcnt vmcnt(4)" ::: "memory");  // prev A1,B1 landed
        __builtin_amdgcn_s_barrier();
        FENCE();                                // reads below need the barrier
        RD_ALO(aL2, d, 1);                      // for ph3
        RD_B(b1, d, 1);
        __builtin_amdgcn_s_setprio(1);
        MFMA_BLK(4, aH, b0);
        __builtin_amdgcn_s_setprio(0);
        __builtin_amdgcn_s_barrier();

        // ---------------- phase 3 ----------------
        STAGE_A(sd, 1, ko);
        __builtin_amdgcn_s_barrier();
        RD_AHI(aH2, d, 1);                      // for ph4
        __builtin_amdgcn_s_setprio(1);
        MFMA_BLK(0, aL2, b1);
        __builtin_amdgcn_s_setprio(0);
        __builtin_amdgcn_s_barrier();

        // ---------------- phase 4 ----------------
        STAGE_B(sd, 1, ko);
        asm volatile("s_waitcnt vmcnt(4)" ::: "memory");  // this A0,B0 landed
        __builtin_amdgcn_s_barrier();
        FENCE();                                // reads below need the barrier
        RD_ALO(aL, sd, 0);                      // for next tile's ph1
        RD_B(b0, sd, 0);
        __builtin_amdgcn_s_setprio(1);
        MFMA_BLK(4, aH2, b1);
        __builtin_amdgcn_s_setprio(0);
        __builtin_amdgcn_s_barrier();
    }
#undef STAGE_A
#undef STAGE_B

    // Epilogue. C/D layout (16x16): col = lane&15, row = (lane>>4)*4 + reg.
#pragma unroll
    for (int n = 0; n < 4; ++n) {
        const int col = col0 + wc * 64 + n * 16 + lr;
        const float bv = bias[col];
#pragma unroll
        for (int m = 0; m < 8; ++m) {
            const int rb = row0 + wr * 128 + m * 16 + g * 4;
#pragma unroll
            for (int r = 0; r < 4; ++r)
                out[(size_t)(rb + r) * NOUT + col] = (float)acc[m][n][r] + bv;
        }
    }
}

// ---------------------------------------------------------------------------
extern "C" void kernel_launch(void* const* d_in, const int* in_sizes, int n_in,
                              void* d_out, int out_size, void* d_ws, size_t ws_size,
                              hipStream_t stream) {
    const float* x = (const float*)d_in[0];   // [8192, 4096]
    const float* w = (const float*)d_in[1];   // [4096, 4096]
    const float* b = (const float*)d_in[2];   // [4096]
    float* out = (float*)d_out;               // [8192, 4096]

    // Workspace: xq 32 MiB + wq 16 MiB of i8 (+-1).
    uint8_t* xq = (uint8_t*)d_ws;
    uint8_t* wq = xq + (size_t)NROW * KDIM;
    (void)ws_size;

    const int n4x = NROW * KDIM / 4;
    const int n4t = n4x + NOUT * KDIM / 4;
    bin_i8_fused<<<3072, 256, 0, stream>>>(x, w, (uint32_t*)xq, (uint32_t*)wq,
                                           n4x, n4t);

    dim3 grid(NOUT / BN, NROW / BM);   // 16 x 32 = 512 blocks
    i8_mfma_gemm<<<grid, 512, 0, stream>>>(xq, wq, b, out);
}

// Round 6
// 403.691 us; speedup vs baseline: 1.0851x; 1.0851x over previous
//
#include <hip/hip_runtime.h>
#include <stdint.h>

// Problem constants: x[8192,4096] f32, w[4096,4096] f32, bias[4096] f32.
#define NROW 8192
#define KDIM 4096
#define NOUT 4096

typedef __attribute__((ext_vector_type(4))) int i32x4;

// ---------------------------------------------------------------------------
// Kernel 1: sign-binarize f32 -> i8 {-1,+1} (bytes 0x01 / 0xFF), 4 per u32.
// One fused launch for x and w. float4 load -> u32 store, BW-bound.
// ---------------------------------------------------------------------------
__global__ __launch_bounds__(256)
void bin_i8_fused(const float* __restrict__ x, const float* __restrict__ w,
                  uint32_t* __restrict__ xq, uint32_t* __restrict__ wq,
                  int n4x, int n4tot) {
    int i = blockIdx.x * blockDim.x + threadIdx.x;
    const int stride = gridDim.x * blockDim.x;
    for (; i < n4tot; i += stride) {
        const float4* src;
        uint32_t* dst;
        int j;
        if (i < n4x) { src = (const float4*)x; dst = xq; j = i; }
        else         { src = (const float4*)w; dst = wq; j = i - n4x; }
        float4 v = src[j];
        uint32_t b0 = (v.x < 0.0f) ? 0xFFu : 0x01u;
        uint32_t b1 = (v.y < 0.0f) ? 0xFFu : 0x01u;
        uint32_t b2 = (v.z < 0.0f) ? 0xFFu : 0x01u;
        uint32_t b3 = (v.w < 0.0f) ? 0xFFu : 0x01u;
        dst[j] = b0 | (b1 << 8) | (b2 << 16) | (b3 << 24);
    }
}

// ---------------------------------------------------------------------------
// Kernel 2: i8 MFMA GEMM — single-barrier-per-K-tile, 4-buffer LDS pipeline.
//   C[n,o] = sum_k xq[n,k]*wq[o,k] + bias[o]   (exact i32 accumulate)
//
// r5 post-mortem: the 8-phase lockstep (256 barriers/block) serialized
// LDS-drain vs MFMA-burst regardless of where reads were placed at source
// (~2000 cy/tile of pure barrier overhead). This version removes the phase
// structure entirely:
//
// Geometry: 256x256 tile, 512 threads = 8 waves (2Mx4N), per-wave 128x64 out
// = 8x4 frags of mfma_i32_16x16x64_i8. BK=64 bytes -> one MFMA per (m,n)
// per K-tile = 32 MFMA + 12 ds_read_b128 per wave per tile, in ONE
// scheduling region (compiler interleaves with fine-grained lgkmcnt).
//
// LDS: 4 buffers x ([256][64] A + [256][64] B) = 128 KiB. Stage 2 tiles
// ahead. Per K-tile t:
//   STAGE(buf[(t+2)&3], tile t+2)      // 4 x global_load_lds (16B)
//   s_waitcnt vmcnt(8)                 // retires the batch staged at t-2
//                                      //   = buf[t&3]'s fill (4+4 newer stay)
//   s_barrier                          // all waves' fills visible (RAW)
//   12 x ds_read_b128 from buf[t&3]; 32 x MFMA   // no trailing barrier
// Hazards:
//   RAW buf[t&3]: own vmcnt(8) + barrier (other waves' loads).  ✓
//   WAR buf[(t+2)&3]: its last reads were at tile t-2, lgkm-drained by
//     t-2's MFMA uses, which precede the t-1 barrier, which precedes this
//     STAGE (per-wave program order).  ✓
// vmcnt never drains to 0 in the loop (always >=8 outstanding at the wait).
//
// Bank swizzle (r2/r4-verified, measured 0 conflicts): LDS slot s_l of row r
// holds global k-chunk s_l ^ ((r>>1)&3); linear gload_lds dest + pre-swizzled
// GLOBAL source; read slot = g ^ ((lr>>1)&3). Per 16-lane read group the
// bank-quad map (lr&1,(lr>>1)&3) covers all 8 quads exactly twice -> free.
// ---------------------------------------------------------------------------
#define BM 256
#define BN 256
#define BKB 64
#define NT (KDIM / BKB)   // 64

__device__ __forceinline__ void gload_lds16(const void* g, void* l) {
    __builtin_amdgcn_global_load_lds(
        (const __attribute__((address_space(1))) uint32_t*)g,
        (__attribute__((address_space(3))) uint32_t*)l, 16, 0, 0);
}

__global__ __launch_bounds__(512, 2)
void i8_mfma_gemm(const uint8_t* __restrict__ xq, const uint8_t* __restrict__ wq,
                  const float* __restrict__ bias, float* __restrict__ out) {
    __shared__ __align__(16) uint8_t As[4][256][64];   // 64 KiB
    __shared__ __align__(16) uint8_t Bs[4][256][64];   // 64 KiB

    const int tid  = threadIdx.x;
    const int wid  = tid >> 6;        // 0..7
    const int lane = tid & 63;
    const int wr   = wid >> 2;        // 0..1 : 128-row slab
    const int wc   = wid & 3;         // 0..3 : 64-col slab
    const int lr   = lane & 15;
    const int g    = lane >> 4;       // k-chunk 0..3 within the 64B row
    const int row0 = blockIdx.y * BM;
    const int col0 = blockIdx.x * BN;

    // Staging: one K-tile of A (or B) = 256 rows x 64B = 1024 chunks of 16B;
    // 2 chunks per thread. LDS dest linear in chunk index; global k-slot
    // pre-swizzled (inverse): row = c>>2, s_g = (c&3) ^ ((c>>3)&3).
    const int c0 = wid * 64 + lane;   // 0..511
    const int c1 = 512 + c0;          // 512..1023
    const int s0 = (((c0 & 3) ^ ((c0 >> 3) & 3))) * 16;
    const int s1 = (((c1 & 3) ^ ((c1 >> 3) & 3))) * 16;
    const int r0 = c0 >> 2;
    const int r1 = c1 >> 2;

    const uint8_t* gA0 = xq + (size_t)(row0 + r0) * KDIM + s0;
    const uint8_t* gA1 = xq + (size_t)(row0 + r1) * KDIM + s1;
    const uint8_t* gB0 = wq + (size_t)(col0 + r0) * KDIM + s0;
    const uint8_t* gB1 = wq + (size_t)(col0 + r1) * KDIM + s1;

    const int sread = (g ^ ((lr >> 1) & 3)) * 16;   // swizzled read slot
    const int ra = wr * 128 + lr;                   // A fragment base row
    const int cb = wc * 64 + lr;                    // B fragment base col

    // One batch = 4 loads (A:2, B:2), issue order fixed for vmcnt accounting.
#define STAGE(sb, ko) do {                                        \
        uint8_t* _la = &As[sb][0][0];                             \
        uint8_t* _lb = &Bs[sb][0][0];                             \
        gload_lds16(gA0 + (ko), _la + c0 * 16);                   \
        gload_lds16(gA1 + (ko), _la + c1 * 16);                   \
        gload_lds16(gB0 + (ko), _lb + c0 * 16);                   \
        gload_lds16(gB1 + (ko), _lb + c1 * 16);                   \
    } while (0)
#define FENCE() asm volatile("" ::: "memory")

    i32x4 acc[8][4];
#pragma unroll
    for (int m = 0; m < 8; ++m)
#pragma unroll
        for (int n = 0; n < 4; ++n) acc[m][n] = (i32x4){0, 0, 0, 0};

    // Prologue: stage tiles 0 and 1 (8 loads outstanding).
    STAGE(0, 0);
    STAGE(1, BKB);

#pragma unroll 1
    for (int t = 0; t < NT; ++t) {
        const int rb = t & 3;
        const int sb = (t + 2) & 3;
        const int ko = (t + 2 < NT ? t + 2 : NT - 1) * BKB;

        STAGE(sb, ko);                                    // 4 loads
        asm volatile("s_waitcnt vmcnt(8)" ::: "memory");  // buf[rb] filled
        __builtin_amdgcn_s_barrier();                     // ...for all waves
        FENCE();

        i32x4 af[8], bf[4];
#pragma unroll
        for (int m = 0; m < 8; ++m)
            af[m] = *(const i32x4*)&As[rb][ra + m * 16][sread];
#pragma unroll
        for (int n = 0; n < 4; ++n)
            bf[n] = *(const i32x4*)&Bs[rb][cb + n * 16][sread];

        __builtin_amdgcn_s_setprio(1);
#pragma unroll
        for (int m = 0; m < 8; ++m)
#pragma unroll
            for (int n = 0; n < 4; ++n)
                acc[m][n] = __builtin_amdgcn_mfma_i32_16x16x64_i8(
                    af[m], bf[n], acc[m][n], 0, 0, 0);
        __builtin_amdgcn_s_setprio(0);
        // No trailing barrier: next tile's STAGE targets buf[(t+3)&3], whose
        // last reads (tile t-1) are lgkm-retired before this tile's barrier.
    }
#undef STAGE

    // Epilogue. C/D layout (16x16): col = lane&15, row = (lane>>4)*4 + reg.
#pragma unroll
    for (int n = 0; n < 4; ++n) {
        const int col = col0 + wc * 64 + n * 16 + lr;
        const float bv = bias[col];
#pragma unroll
        for (int m = 0; m < 8; ++m) {
            const int rb2 = row0 + wr * 128 + m * 16 + g * 4;
#pragma unroll
            for (int r = 0; r < 4; ++r)
                out[(size_t)(rb2 + r) * NOUT + col] = (float)acc[m][n][r] + bv;
        }
    }
}

// ---------------------------------------------------------------------------
extern "C" void kernel_launch(void* const* d_in, const int* in_sizes, int n_in,
                              void* d_out, int out_size, void* d_ws, size_t ws_size,
                              hipStream_t stream) {
    const float* x = (const float*)d_in[0];   // [8192, 4096]
    const float* w = (const float*)d_in[1];   // [4096, 4096]
    const float* b = (const float*)d_in[2];   // [4096]
    float* out = (float*)d_out;               // [8192, 4096]

    // Workspace: xq 32 MiB + wq 16 MiB of i8 (+-1).
    uint8_t* xq = (uint8_t*)d_ws;
    uint8_t* wq = xq + (size_t)NROW * KDIM;
    (void)ws_size;

    const int n4x = NROW * KDIM / 4;
    const int n4t = n4x + NOUT * KDIM / 4;
    bin_i8_fused<<<3072, 256, 0, stream>>>(x, w, (uint32_t*)xq, (uint32_t*)wq,
                                           n4x, n4t);

    dim3 grid(NOUT / BN, NROW / BM);   // 16 x 32 = 512 blocks
    i8_mfma_gemm<<<grid, 512, 0, stream>>>(xq, wq, b, out);
}

// Round 7
// 375.912 us; speedup vs baseline: 1.1652x; 1.0739x over previous
//
#include <hip/hip_runtime.h>
#include <stdint.h>

// Problem constants: x[8192,4096] f32, w[4096,4096] f32, bias[4096] f32.
#define NROW 8192
#define KDIM 4096
#define NOUT 4096

typedef __attribute__((ext_vector_type(4))) int i32x4;

// ---------------------------------------------------------------------------
// Kernel 1: sign-binarize f32 -> i8 {-1,+1} (bytes 0x01 / 0xFF), 4 per u32.
// Block-range split (uniform per block, no per-iteration branch):
//   blocks [0, XBLK)      -> x -> xq
//   blocks [XBLK, total)  -> w -> wq
// Each thread-iter: one float4 load (16B) -> one u32 store. Pure BW-bound.
// ---------------------------------------------------------------------------
#define XBLK 2048
#define WBLK 1024

__global__ __launch_bounds__(256)
void bin_i8_fused(const float* __restrict__ x, const float* __restrict__ w,
                  uint32_t* __restrict__ xq, uint32_t* __restrict__ wq,
                  int n4x, int n4w) {
    const float4* src;
    uint32_t* dst;
    int n4, i, stride;
    if (blockIdx.x < XBLK) {
        src = (const float4*)x; dst = xq; n4 = n4x;
        i = blockIdx.x * blockDim.x + threadIdx.x;
        stride = XBLK * blockDim.x;
    } else {
        src = (const float4*)w; dst = wq; n4 = n4w;
        i = (blockIdx.x - XBLK) * blockDim.x + threadIdx.x;
        stride = WBLK * blockDim.x;
    }
    for (; i < n4; i += stride) {
        float4 v = src[i];
        uint32_t b0 = (v.x < 0.0f) ? 0xFFu : 0x01u;
        uint32_t b1 = (v.y < 0.0f) ? 0xFFu : 0x01u;
        uint32_t b2 = (v.z < 0.0f) ? 0xFFu : 0x01u;
        uint32_t b3 = (v.w < 0.0f) ? 0xFFu : 0x01u;
        dst[i] = b0 | (b1 << 8) | (b2 << 16) | (b3 << 24);
    }
}

// ---------------------------------------------------------------------------
// Kernel 2: i8 MFMA GEMM — one barrier per TWO K-tiles, 4-buffer pipeline.
//   C[n,o] = sum_k xq[n,k]*wq[o,k] + bias[o]   (exact i32 accumulate)
//
// r6 post-mortem: 1 barrier/tile left a serial vmcnt->barrier->ds_read->MFMA
// chain per tile (38% MfmaUtil vs 45% structural cap). Now each barrier
// publishes TWO resident tiles; the merged region holds two independent
// {12 ds_read + 32 MFMA} sets, so tile t+1's reads drain under tile t's
// MFMAs via counted lgkmcnt. Barriers: 64 -> 32 per block.
//
// Geometry: 256x256 tile, 512 threads = 8 waves (2Mx4N), per-wave 128x64 out
// = 8x4 frags of mfma_i32_16x16x64_i8. BK=64 B. LDS: 4 bufs x (A[256][64] +
// B[256][64]) = 128 KiB. Stage 2 tiles ahead.
//
// Per pair {t, t+1} (t even):
//   STAGE(buf[(t+2)&3], t+2); STAGE(buf[(t+3)&3], t+3)   // 8 loads
//   s_waitcnt vmcnt(8)    // retires batches t, t+1 (t+2,t+3 stay in flight)
//   s_barrier             // all waves' fills of bufs t,t+1 visible
//   reads(t); reads(t+1); MFMA(t); MFMA(t+1)             // one region
// Hazards:
//   RAW bufs t,t+1: own vmcnt(8) + barrier (others' loads).  OK
//   WAR bufs (t+2)&3,(t+3)&3: last read at tiles t-2,t-1; those reads
//     completed before their MFMAs issued, which precede the PREVIOUS
//     barrier; this STAGE is after it.  OK
// vmcnt never drains to 0 in the loop.
//
// Bank swizzle (r2/r4/r6-verified, 0 conflicts): LDS slot s_l of row r holds
// global k-chunk s_l ^ ((r>>1)&3); linear gload_lds dest + pre-swizzled
// GLOBAL source; read slot = g ^ ((lr>>1)&3).
// ---------------------------------------------------------------------------
#define BM 256
#define BN 256
#define BKB 64
#define NT (KDIM / BKB)   // 64 (even)

__device__ __forceinline__ void gload_lds16(const void* g, void* l) {
    __builtin_amdgcn_global_load_lds(
        (const __attribute__((address_space(1))) uint32_t*)g,
        (__attribute__((address_space(3))) uint32_t*)l, 16, 0, 0);
}

__global__ __launch_bounds__(512, 2)
void i8_mfma_gemm(const uint8_t* __restrict__ xq, const uint8_t* __restrict__ wq,
                  const float* __restrict__ bias, float* __restrict__ out) {
    __shared__ __align__(16) uint8_t As[4][256][64];   // 64 KiB
    __shared__ __align__(16) uint8_t Bs[4][256][64];   // 64 KiB

    const int tid  = threadIdx.x;
    const int wid  = tid >> 6;        // 0..7
    const int lane = tid & 63;
    const int wr   = wid >> 2;        // 0..1 : 128-row slab
    const int wc   = wid & 3;         // 0..3 : 64-col slab
    const int lr   = lane & 15;
    const int g    = lane >> 4;       // k-chunk 0..3 within the 64B row
    const int row0 = blockIdx.y * BM;
    const int col0 = blockIdx.x * BN;

    // Staging: one K-tile of A (or B) = 256 rows x 64B = 1024 chunks of 16B;
    // 2 chunks per thread. LDS dest linear in chunk index; global k-slot
    // pre-swizzled (inverse): row = c>>2, s_g = (c&3) ^ ((c>>3)&3).
    const int c0 = wid * 64 + lane;   // 0..511
    const int c1 = 512 + c0;          // 512..1023
    const int s0 = (((c0 & 3) ^ ((c0 >> 3) & 3))) * 16;
    const int s1 = (((c1 & 3) ^ ((c1 >> 3) & 3))) * 16;
    const int r0 = c0 >> 2;
    const int r1 = c1 >> 2;

    const uint8_t* gA0 = xq + (size_t)(row0 + r0) * KDIM + s0;
    const uint8_t* gA1 = xq + (size_t)(row0 + r1) * KDIM + s1;
    const uint8_t* gB0 = wq + (size_t)(col0 + r0) * KDIM + s0;
    const uint8_t* gB1 = wq + (size_t)(col0 + r1) * KDIM + s1;

    const int sread = (g ^ ((lr >> 1) & 3)) * 16;   // swizzled read slot
    const int ra = wr * 128 + lr;                   // A fragment base row
    const int cb = wc * 64 + lr;                    // B fragment base col

    // One batch = 4 loads (A:2, B:2), fixed issue order for vmcnt accounting.
#define STAGE(sb, ko) do {                                        \
        uint8_t* _la = &As[sb][0][0];                             \
        uint8_t* _lb = &Bs[sb][0][0];                             \
        gload_lds16(gA0 + (ko), _la + c0 * 16);                   \
        gload_lds16(gA1 + (ko), _la + c1 * 16);                   \
        gload_lds16(gB0 + (ko), _lb + c0 * 16);                   \
        gload_lds16(gB1 + (ko), _lb + c1 * 16);                   \
    } while (0)
#define RD_TILE(af, bf, rb) do {                                        \
        _Pragma("unroll")                                               \
        for (int _m = 0; _m < 8; ++_m)                                  \
            af[_m] = *(const i32x4*)&As[rb][ra + _m * 16][sread];       \
        _Pragma("unroll")                                               \
        for (int _n = 0; _n < 4; ++_n)                                  \
            bf[_n] = *(const i32x4*)&Bs[rb][cb + _n * 16][sread];       \
    } while (0)
#define MFMA_TILE(af, bf) do {                                          \
        _Pragma("unroll")                                               \
        for (int _m = 0; _m < 8; ++_m)                                  \
            _Pragma("unroll")                                           \
            for (int _n = 0; _n < 4; ++_n)                              \
                acc[_m][_n] = __builtin_amdgcn_mfma_i32_16x16x64_i8(    \
                    af[_m], bf[_n], acc[_m][_n], 0, 0, 0);              \
    } while (0)
#define FENCE() asm volatile("" ::: "memory")

    i32x4 acc[8][4];
#pragma unroll
    for (int m = 0; m < 8; ++m)
#pragma unroll
        for (int n = 0; n < 4; ++n) acc[m][n] = (i32x4){0, 0, 0, 0};

    // Prologue: stage tiles 0 and 1 (8 loads outstanding).
    STAGE(0, 0);
    STAGE(1, BKB);

#pragma unroll 1
    for (int t = 0; t < NT; t += 2) {
        const int rb0 = t & 3;
        const int rb1 = (t + 1) & 3;
        const int sb0 = (t + 2) & 3;
        const int sb1 = (t + 3) & 3;
        // Tail pairs re-stage the last tile (uniform vmcnt counts; the
        // target bufs are never read again -> harmless).
        const int ko0 = ((t + 2) < NT ? (t + 2) : (NT - 1)) * BKB;
        const int ko1 = ((t + 3) < NT ? (t + 3) : (NT - 1)) * BKB;

        STAGE(sb0, ko0);                                  // 4 loads
        STAGE(sb1, ko1);                                  // 4 loads
        asm volatile("s_waitcnt vmcnt(8)" ::: "memory");  // bufs rb0,rb1 in
        __builtin_amdgcn_s_barrier();                     // ...for all waves
        FENCE();

        i32x4 af0[8], bf0[4], af1[8], bf1[4];
        RD_TILE(af0, bf0, rb0);
        RD_TILE(af1, bf1, rb1);

        __builtin_amdgcn_s_setprio(1);
        MFMA_TILE(af0, bf0);
        MFMA_TILE(af1, bf1);
        __builtin_amdgcn_s_setprio(0);
        // No trailing barrier: the next pair's STAGE targets bufs whose last
        // reads completed before THIS barrier (see header).
    }
#undef STAGE

    // Epilogue. C/D layout (16x16): col = lane&15, row = (lane>>4)*4 + reg.
#pragma unroll
    for (int n = 0; n < 4; ++n) {
        const int col = col0 + wc * 64 + n * 16 + lr;
        const float bv = bias[col];
#pragma unroll
        for (int m = 0; m < 8; ++m) {
            const int rb2 = row0 + wr * 128 + m * 16 + g * 4;
#pragma unroll
            for (int r = 0; r < 4; ++r)
                out[(size_t)(rb2 + r) * NOUT + col] = (float)acc[m][n][r] + bv;
        }
    }
}

// ---------------------------------------------------------------------------
extern "C" void kernel_launch(void* const* d_in, const int* in_sizes, int n_in,
                              void* d_out, int out_size, void* d_ws, size_t ws_size,
                              hipStream_t stream) {
    const float* x = (const float*)d_in[0];   // [8192, 4096]
    const float* w = (const float*)d_in[1];   // [4096, 4096]
    const float* b = (const float*)d_in[2];   // [4096]
    float* out = (float*)d_out;               // [8192, 4096]

    // Workspace: xq 32 MiB + wq 16 MiB of i8 (+-1).
    uint8_t* xq = (uint8_t*)d_ws;
    uint8_t* wq = xq + (size_t)NROW * KDIM;
    (void)ws_size;

    const int n4x = NROW * KDIM / 4;
    const int n4w = NOUT * KDIM / 4;
    bin_i8_fused<<<XBLK + WBLK, 256, 0, stream>>>(x, w, (uint32_t*)xq,
                                                  (uint32_t*)wq, n4x, n4w);

    dim3 grid(NOUT / BN, NROW / BM);   // 16 x 32 = 512 blocks
    i8_mfma_gemm<<<grid, 512, 0, stream>>>(xq, wq, b, out);
}